// Round 1
// baseline (891.582 us; speedup 1.0000x reference)
//
#include <hip/hip_runtime.h>
#include <math.h>

#define NAG 16
#define OBSD 128
#define STATED 256
#define NHIDD 32
#define ALPHA 0.2f
#define NEGV -9.0e15f
#define BTOT 8192
#define XCOLS 560   // 512 b_all + 16 dis + 32 v1

__device__ __forceinline__ float lrelu(float x){ return x > 0.f ? x : ALPHA*x; }
__device__ __forceinline__ float eluf(float x){ return x > 0.f ? x : (expf(x)-1.f); }

// ---------------- prep: WstT[s][c] = fused state-side weight, transposed ----------------
__global__ void prep_kernel(const float* __restrict__ hb_W,   // [512][256] (n*32+e major)
                            const float* __restrict__ wn_w,   // [16][256]
                            const float* __restrict__ v1_w,   // [32][256]
                            float* __restrict__ WstT){        // [256][560]
  int idx = blockIdx.x*256 + threadIdx.x;
  if (idx >= STATED*XCOLS) return;
  int s = idx / XCOLS, c = idx - s*XCOLS;
  float v;
  if (c < 512)      v = hb_W[c*STATED + s];
  else if (c < 528) v = wn_w[(c-512)*STATED + s];
  else              v = v1_w[(c-528)*STATED + s];
  WstT[idx] = v;
}

// ---------------- kernel 1: per-batch state projections (b_all, dis, V) ----------------
__global__ __launch_bounds__(256) void st_kernel(
    const float* __restrict__ states,   // [8192][256]
    const float* __restrict__ WstT,     // [256][560]
    const float* __restrict__ hb_b,     // [512]
    const float* __restrict__ wn_b,     // [16]
    const float* __restrict__ v1_b,     // [32]
    const float* __restrict__ v2_w,     // [32]
    const float* __restrict__ v2_b,     // [1]
    float* __restrict__ b_all,          // [8192][512]
    float* __restrict__ dis,            // [8192][16]
    float* __restrict__ vv){            // [8192]
  __shared__ __align__(16) float stT[STATED][16];
  __shared__ float vh[16][NHIDD];
  const int t = threadIdx.x;
  const int b0 = blockIdx.x*16;
  const float4* src = reinterpret_cast<const float4*>(states + (size_t)b0*STATED);
  #pragma unroll
  for (int v4=0; v4<4; ++v4){
    float4 f = src[t + v4*256];
    int e = (t + v4*256)*4;
    int bb = e >> 8, ss = e & 255;
    stT[ss][bb]=f.x; stT[ss+1][bb]=f.y; stT[ss+2][bb]=f.z; stT[ss+3][bb]=f.w;
  }
  __syncthreads();
  for (int pass=0; pass<3; ++pass){
    int c = pass*256 + t;
    if (c < XCOLS){
      float acc[16];
      #pragma unroll
      for (int i=0;i<16;++i) acc[i]=0.f;
      for (int s=0;s<STATED;++s){
        float w = WstT[s*XCOLS + c];
        #pragma unroll
        for (int q=0;q<4;++q){
          float4 r = reinterpret_cast<const float4*>(&stT[s][0])[q];
          acc[q*4+0]+=r.x*w; acc[q*4+1]+=r.y*w; acc[q*4+2]+=r.z*w; acc[q*4+3]+=r.w*w;
        }
      }
      if (c < 512){
        float bb = hb_b[c];
        #pragma unroll
        for (int i=0;i<16;++i) b_all[(size_t)(b0+i)*512 + c] = acc[i] + bb;
      } else if (c < 528){
        float bb = wn_b[c-512];
        #pragma unroll
        for (int i=0;i<16;++i) dis[(b0+i)*NAG + (c-512)] = fabsf(acc[i] + bb);
      } else {
        float bb = v1_b[c-528];
        #pragma unroll
        for (int i=0;i<16;++i) vh[i][c-528] = fmaxf(acc[i] + bb, 0.f);
      }
    }
  }
  __syncthreads();
  if (t < 16){
    float s = v2_b[0];
    #pragma unroll
    for (int e=0;e<32;++e) s += vh[t][e]*v2_w[e];
    vv[b0+t] = s;
  }
}

// ---------------- kernel 2: full dual-GAT + mixing, one block per batch element ----------------
__global__ __launch_bounds__(256,2) void gat_kernel(
    const float* __restrict__ agent_qs,
    const float* __restrict__ obs_ls,
    const float* __restrict__ adj_ls,
    const float* __restrict__ g1_Wh, const float* __restrict__ g1_ah,
    const float* __restrict__ g1_Wout, const float* __restrict__ g1_aout,
    const float* __restrict__ gf_Wh, const float* __restrict__ gf_ah,
    const float* __restrict__ gf_Wout, const float* __restrict__ gf_aout,
    const float* __restrict__ b_all_ws, const float* __restrict__ dis_ws,
    const float* __restrict__ vv_ws,
    float* __restrict__ out){
  __shared__ __align__(16) float obsT[OBSD*16];   // [k][r]; reused for Wh2f/o2f later
  __shared__ __align__(16) float adj_s[256];      // [i][j]
  __shared__ float qs_s[16];
  __shared__ __align__(16) float WhA[16*256];     // [r][g*32+c]
  __shared__ float u_s[128], v_s[128];            // [g*16+i]
  __shared__ __align__(16) float attT[8*256];     // [g][j][i]
  __shared__ __align__(16) float xcatT[256*20];   // [col][i], stride 20; reused as part[8][512]
  __shared__ float u2_s[16], v2_s[16];
  __shared__ __align__(16) float att2T[256];      // [j][i]
  __shared__ float red_s[128];                    // [wave][32]
  __shared__ float hypwf[512];                    // [i*32+c]
  __shared__ float prod_s[512];
  __shared__ float y_s[16];

  const int t = threadIdx.x;
  const int b = blockIdx.x;

  // ---- loads (obs transposed into LDS) ----
  {
    const float4* src = reinterpret_cast<const float4*>(obs_ls + (size_t)b*(NAG*OBSD));
    #pragma unroll
    for (int v4=0; v4<2; ++v4){
      float4 f = src[t + v4*256];
      int e = (t + v4*256)*4;
      int r = e >> 7, k = e & 127;
      obsT[k*16 + r]     = f.x;
      obsT[(k+1)*16 + r] = f.y;
      obsT[(k+2)*16 + r] = f.z;
      obsT[(k+3)*16 + r] = f.w;
    }
    if (t < 64) reinterpret_cast<float4*>(adj_s)[t] =
        reinterpret_cast<const float4*>(adj_ls + (size_t)b*256)[t];
    if (t < 16) qs_s[t] = agent_qs[b*NAG + t];
  }
  __syncthreads();

  // ---- Phase 1: Wh = obs @ W  (8 head-instances: g<4 -> g1, g>=4 -> gf) ----
  {
    int g = t >> 5, c = t & 31;
    const float* W = (g < 4) ? (g1_Wh + g*OBSD*NHIDD) : (gf_Wh + (g-4)*OBSD*NHIDD);
    float acc[16];
    #pragma unroll
    for (int i=0;i<16;++i) acc[i]=0.f;
    #pragma unroll 2
    for (int k=0;k<OBSD;++k){
      float w = W[k*NHIDD + c];
      #pragma unroll
      for (int q=0;q<4;++q){
        float4 r = reinterpret_cast<const float4*>(&obsT[k*16])[q];
        acc[q*4+0]+=r.x*w; acc[q*4+1]+=r.y*w; acc[q*4+2]+=r.z*w; acc[q*4+3]+=r.w*w;
      }
    }
    #pragma unroll
    for (int i=0;i<16;++i) WhA[i*256 + t] = acc[i];
  }
  __syncthreads();

  // ---- u,v per (head-instance, agent) ----
  {
    int g = t >> 5, i = (t >> 1) & 15, which = t & 1;
    const float* a = ((g < 4) ? (g1_ah + g*64) : (gf_ah + (g-4)*64)) + which*32;
    float s = 0.f;
    int base = i*256 + g*32;
    #pragma unroll
    for (int c=0;c<32;++c) s += WhA[base+c]*a[c];
    if (which == 0) u_s[g*16+i] = s; else v_s[g*16+i] = s;
  }
  __syncthreads();

  // ---- Phase 2: att = softmax_i( mask(lrelu(u_i+v_j)) ), stored [g][j][i] ----
  if (t < 128){
    int g = t >> 4, j = t & 15;
    float vj = v_s[g*16+j];
    float ev[16]; float m = -INFINITY;
    #pragma unroll
    for (int i=0;i<16;++i){
      float x = lrelu(u_s[g*16+i] + vj);
      x = (adj_s[i*16+j] > 0.f) ? x : NEGV;
      ev[i]=x; m = fmaxf(m,x);
    }
    float ssum = 0.f;
    #pragma unroll
    for (int i=0;i<16;++i){ ev[i]=expf(ev[i]-m); ssum+=ev[i]; }
    float inv = 1.f/ssum;
    #pragma unroll
    for (int i=0;i<16;++i) attT[g*256 + j*16 + i] = ev[i]*inv;
  }
  __syncthreads();

  // ---- Phase 3: xcat = elu(att @ Wh), stored transposed [col][i] stride 20 ----
  {
    int g = t >> 5, c = t & 31;
    float acc[16];
    #pragma unroll
    for (int i=0;i<16;++i) acc[i]=0.f;
    #pragma unroll 4
    for (int j=0;j<16;++j){
      float w = WhA[j*256 + g*32 + c];
      #pragma unroll
      for (int q=0;q<4;++q){
        float4 r = reinterpret_cast<const float4*>(&attT[g*256 + j*16])[q];
        acc[q*4+0]+=r.x*w; acc[q*4+1]+=r.y*w; acc[q*4+2]+=r.z*w; acc[q*4+3]+=r.w*w;
      }
    }
    #pragma unroll
    for (int i=0;i<16;++i) xcatT[t*20 + i] = eluf(acc[i]);
  }
  __syncthreads();

  // ---- Phase 4b: gf second layer GEMM -> Wh2f[16][36] (reuses obsT region) ----
  float* Wh2f = obsT;          // 576 floats
  float* o2f  = obsT + 640;    // 576 floats
  {
    int c = t & 31, r0 = t >> 5;
    float a0=0.f, a1=0.f;
    #pragma unroll 2
    for (int k=0;k<OBSD;++k){
      float w = gf_Wout[k*32 + c];
      a0 += xcatT[(128+k)*20 + r0]*w;
      a1 += xcatT[(128+k)*20 + r0+8]*w;
    }
    Wh2f[r0*36 + c] = a0;
    Wh2f[(r0+8)*36 + c] = a1;
  }
  __syncthreads();
  if (t < 32){   // gf u2/v2
    int which = t >> 4, i = t & 15;
    const float* a = gf_aout + which*32;
    float s = 0.f;
    #pragma unroll
    for (int c=0;c<32;++c) s += Wh2f[i*36+c]*a[c];
    if (which==0) u2_s[i]=s; else v2_s[i]=s;
  }
  __syncthreads();
  if (t < 16){   // gf att2
    int j = t;
    float vj = v2_s[j];
    float ev[16]; float m=-INFINITY;
    #pragma unroll
    for (int i=0;i<16;++i){
      float x = lrelu(u2_s[i]+vj);
      x = (adj_s[i*16+j] > 0.f) ? x : NEGV;
      ev[i]=x; m=fmaxf(m,x);
    }
    float ssum=0.f;
    #pragma unroll
    for (int i=0;i<16;++i){ ev[i]=expf(ev[i]-m); ssum+=ev[i]; }
    float inv=1.f/ssum;
    #pragma unroll
    for (int i=0;i<16;++i) att2T[j*16+i] = ev[i]*inv;
  }
  __syncthreads();
  {   // gf o2 = elu(att2 @ Wh2f)
    int c = t & 31, i0 = t >> 5;
    #pragma unroll
    for (int ii=0; ii<2; ++ii){
      int i = i0 + ii*8;
      float s = 0.f;
      #pragma unroll
      for (int j=0;j<16;++j) s += att2T[j*16+i]*Wh2f[j*36+c];
      o2f[i*36+c] = eluf(s);
    }
  }
  __syncthreads();
  if (t < 32){   // gf log_softmax over agents, abs -> hypwf
    int c = t;
    float m = -INFINITY;
    #pragma unroll
    for (int i=0;i<16;++i) m = fmaxf(m, o2f[i*36+c]);
    float ssum = 0.f;
    #pragma unroll
    for (int i=0;i<16;++i) ssum += expf(o2f[i*36+c]-m);
    float ls = m + logf(ssum);
    #pragma unroll
    for (int i=0;i<16;++i) hypwf[i*32+c] = fabsf(o2f[i*36+c]-ls);
  }
  // no sync needed here: hypwf consumed only after later syncs; att2T/u2_s rewritten after syncs

  // ---- Phase 4a: g1 second layer GEMM; thread owns cols c0=t, c1=t+256 ----
  float acc0[16], acc1[16];
  {
    #pragma unroll
    for (int i=0;i<16;++i){acc0[i]=0.f; acc1[i]=0.f;}
    const int c0 = t, c1 = t+256;
    #pragma unroll 2
    for (int k=0;k<OBSD;++k){
      float w0 = g1_Wout[k*512 + c0];
      float w1 = g1_Wout[k*512 + c1];
      #pragma unroll
      for (int q=0;q<4;++q){
        float4 r = reinterpret_cast<const float4*>(&xcatT[k*20])[q];
        acc0[q*4+0]+=r.x*w0; acc0[q*4+1]+=r.y*w0; acc0[q*4+2]+=r.z*w0; acc0[q*4+3]+=r.w*w0;
        acc1[q*4+0]+=r.x*w1; acc1[q*4+1]+=r.y*w1; acc1[q*4+2]+=r.z*w1; acc1[q*4+3]+=r.w*w1;
      }
    }
    // u2/v2 partials: u2_i = sum_c Wh2[i][c]*a0[c]
    float pu[16], pv[16];
    float a00 = g1_aout[c0], a01 = g1_aout[c1];
    float a10 = g1_aout[512+c0], a11 = g1_aout[512+c1];
    #pragma unroll
    for (int i=0;i<16;++i){ pu[i] = acc0[i]*a00 + acc1[i]*a01; pv[i] = acc0[i]*a10 + acc1[i]*a11; }
    #pragma unroll
    for (int off=1; off<64; off<<=1){
      #pragma unroll
      for (int i=0;i<16;++i){
        pu[i] += __shfl_xor(pu[i], off, 64);
        pv[i] += __shfl_xor(pv[i], off, 64);
      }
    }
    int wid = t >> 6, lane = t & 63;
    if (lane == 0){
      #pragma unroll
      for (int i=0;i<16;++i){ red_s[wid*32+i]=pu[i]; red_s[wid*32+16+i]=pv[i]; }
    }
  }
  __syncthreads();
  if (t < 32){
    int which = t >> 4, i = t & 15;
    float s = 0.f;
    #pragma unroll
    for (int w=0;w<4;++w) s += red_s[w*32 + which*16 + i];
    if (which==0) u2_s[i]=s; else v2_s[i]=s;
  }
  __syncthreads();
  if (t < 16){   // g1 att2
    int j = t;
    float vj = v2_s[j];
    float ev[16]; float m=-INFINITY;
    #pragma unroll
    for (int i=0;i<16;++i){
      float x = lrelu(u2_s[i]+vj);
      x = (adj_s[i*16+j] > 0.f) ? x : NEGV;
      ev[i]=x; m=fmaxf(m,x);
    }
    float ssum=0.f;
    #pragma unroll
    for (int i=0;i<16;++i){ ev[i]=expf(ev[i]-m); ssum+=ev[i]; }
    float inv=1.f/ssum;
    #pragma unroll
    for (int i=0;i<16;++i) att2T[j*16+i] = ev[i]*inv;
  }
  __syncthreads();
  // ---- Phase 5a: o = att2 @ Wh2 (thread-local cols), elu, log_softmax_i, abs, mix partial ----
  {
    float o0[16], o1[16];
    #pragma unroll
    for (int i=0;i<16;++i){o0[i]=0.f;o1[i]=0.f;}
    #pragma unroll 4
    for (int j=0;j<16;++j){
      float w0 = acc0[j], w1 = acc1[j];
      #pragma unroll
      for (int q=0;q<4;++q){
        float4 r = reinterpret_cast<const float4*>(&att2T[j*16])[q];
        o0[q*4+0]+=r.x*w0; o0[q*4+1]+=r.y*w0; o0[q*4+2]+=r.z*w0; o0[q*4+3]+=r.w*w0;
        o1[q*4+0]+=r.x*w1; o1[q*4+1]+=r.y*w1; o1[q*4+2]+=r.z*w1; o1[q*4+3]+=r.w*w1;
      }
    }
    float m0=-INFINITY, m1=-INFINITY;
    #pragma unroll
    for (int i=0;i<16;++i){
      o0[i]=eluf(o0[i]); o1[i]=eluf(o1[i]);
      m0=fmaxf(m0,o0[i]); m1=fmaxf(m1,o1[i]);
    }
    float s0=0.f, s1=0.f;
    #pragma unroll
    for (int i=0;i<16;++i){ s0+=expf(o0[i]-m0); s1+=expf(o1[i]-m1); }
    float ls0 = m0+logf(s0), ls1 = m1+logf(s1);
    int g = t >> 5, e = t & 31;        // c0 = g*32+e (n=g), c1 = (8+g)*32+e (n=8+g)
    float q0 = qs_s[g], q1 = qs_s[8+g];
    float* part = xcatT;               // reuse xcatT as part[8][512]
    #pragma unroll
    for (int i=0;i<16;++i){
      part[g*512 + i*32 + e] = q0*fabsf(o0[i]-ls0) + q1*fabsf(o1[i]-ls1);
    }
  }
  __syncthreads();
  // ---- hidden = elu(sum_n qs_n*w1 + b_all); prod = hidden*hypwf ----
  {
    float* part = xcatT;
    #pragma unroll
    for (int pp=0; pp<2; ++pp){
      int p = t + pp*256;
      float s = b_all_ws[(size_t)b*512 + p];
      #pragma unroll
      for (int g=0; g<8; ++g) s += part[g*512 + p];
      prod_s[p] = eluf(s) * hypwf[p];
    }
  }
  __syncthreads();
  if (t < 16){
    float s = 0.f;
    #pragma unroll
    for (int e=0;e<32;++e) s += prod_s[t*32+e];
    y_s[t] = s * dis_ws[b*NAG + t];
  }
  __syncthreads();
  if (t == 0){
    float q = vv_ws[b];
    #pragma unroll
    for (int j=0;j<16;++j) q += y_s[j];
    out[b] = q;
  }
}

extern "C" void kernel_launch(void* const* d_in, const int* in_sizes, int n_in,
                              void* d_out, int out_size, void* d_ws, size_t ws_size,
                              hipStream_t stream) {
  const float* agent_qs = (const float*)d_in[0];
  const float* states   = (const float*)d_in[1];
  const float* obs_ls   = (const float*)d_in[2];
  const float* adj_ls   = (const float*)d_in[3];
  const float* wn_w     = (const float*)d_in[4];
  const float* wn_b     = (const float*)d_in[5];
  const float* g1_Wh    = (const float*)d_in[6];
  const float* g1_ah    = (const float*)d_in[7];
  const float* g1_Wout  = (const float*)d_in[8];
  const float* g1_aout  = (const float*)d_in[9];
  const float* gf_Wh    = (const float*)d_in[10];
  const float* gf_ah    = (const float*)d_in[11];
  const float* gf_Wout  = (const float*)d_in[12];
  const float* gf_aout  = (const float*)d_in[13];
  const float* hb_W     = (const float*)d_in[14];
  const float* hb_b     = (const float*)d_in[15];
  const float* v1_w     = (const float*)d_in[16];
  const float* v1_b     = (const float*)d_in[17];
  const float* v2_w     = (const float*)d_in[18];
  const float* v2_b     = (const float*)d_in[19];

  float* ws    = (float*)d_ws;
  float* WstT  = ws;                        // 256*560 = 143360
  float* b_all = WstT + STATED*XCOLS;       // 8192*512
  float* dis   = b_all + (size_t)BTOT*512;  // 8192*16
  float* vvv   = dis + (size_t)BTOT*NAG;    // 8192

  prep_kernel<<<dim3((STATED*XCOLS + 255)/256), dim3(256), 0, stream>>>(hb_W, wn_w, v1_w, WstT);
  st_kernel<<<dim3(BTOT/16), dim3(256), 0, stream>>>(states, WstT, hb_b, wn_b, v1_b, v2_w, v2_b,
                                                     b_all, dis, vvv);
  gat_kernel<<<dim3(BTOT), dim3(256), 0, stream>>>(agent_qs, obs_ls, adj_ls,
                                                   g1_Wh, g1_ah, g1_Wout, g1_aout,
                                                   gf_Wh, gf_ah, gf_Wout, gf_aout,
                                                   b_all, dis, vvv, (float*)d_out);
}

// Round 2
// 588.384 us; speedup vs baseline: 1.5153x; 1.5153x over previous
//
#include <hip/hip_runtime.h>
#include <math.h>

#define NAG 16
#define OBSD 128
#define STATED 256
#define ALPHA 0.2f
#define NEGV -9.0e15f
#define BTOT 8192
#define XCOLS 560   // 512 b_all + 16 dis + 32 v1
#define WST 258     // WhA row stride (bank-conflict-free)
#define XST 20      // xcatT / zT column stride

__device__ __forceinline__ float lrelu(float x){ return x > 0.f ? x : ALPHA*x; }
__device__ __forceinline__ float eluf(float x){ return x > 0.f ? x : (__expf(x)-1.f); }

// ---------------- prep: WstT[s][c] = fused state-side weight, transposed ----------------
__global__ void prep_kernel(const float* __restrict__ hb_W,   // [512][256]
                            const float* __restrict__ wn_w,   // [16][256]
                            const float* __restrict__ v1_w,   // [32][256]
                            float* __restrict__ WstT){        // [256][560]
  int idx = blockIdx.x*256 + threadIdx.x;
  if (idx >= STATED*XCOLS) return;
  int s = idx / XCOLS, c = idx - s*XCOLS;
  float v;
  if (c < 512)      v = hb_W[c*STATED + s];
  else if (c < 528) v = wn_w[(c-512)*STATED + s];
  else              v = v1_w[(c-528)*STATED + s];
  WstT[idx] = v;
}

// ---------------- prep2: wa[4][128] = Wout @ aout halves (g1 u/v, gf u/v) ----------------
__global__ void prep2_kernel(const float* __restrict__ g1_Wout, const float* __restrict__ g1_aout,
                             const float* __restrict__ gf_Wout, const float* __restrict__ gf_aout,
                             float* __restrict__ wa){
  int k = threadIdx.x;  // 128
  float su = 0.f, sv = 0.f;
  for (int c = 0; c < 512; ++c){
    float w = g1_Wout[k*512 + c];
    su += w * g1_aout[c];
    sv += w * g1_aout[512 + c];
  }
  wa[k] = su; wa[128 + k] = sv;
  float fu = 0.f, fv = 0.f;
  for (int c = 0; c < 32; ++c){
    float w = gf_Wout[k*32 + c];
    fu += w * gf_aout[c];
    fv += w * gf_aout[32 + c];
  }
  wa[256 + k] = fu; wa[384 + k] = fv;
}

// ---------------- kernel 1: per-batch state projections (b_all, dis, V) ----------------
__global__ __launch_bounds__(256) void st_kernel(
    const float* __restrict__ states,   // [8192][256]
    const float* __restrict__ WstT,     // [256][560]
    const float* __restrict__ hb_b,     // [512]
    const float* __restrict__ wn_b,     // [16]
    const float* __restrict__ v1_b,     // [32]
    const float* __restrict__ v2_w,     // [32]
    const float* __restrict__ v2_b,     // [1]
    float* __restrict__ b_all,          // [8192][512]
    float* __restrict__ dis,            // [8192][16]
    float* __restrict__ vv){            // [8192]
  __shared__ __align__(16) float stT[STATED*16];  // [s][bchunk swizzled]
  __shared__ float vh[16][32];
  const int t = threadIdx.x;
  const int b0 = blockIdx.x*16;
  const float4* src = reinterpret_cast<const float4*>(states + (size_t)b0*STATED);
  #pragma unroll
  for (int v4=0; v4<4; ++v4){
    float4 f = src[t + v4*256];
    int e = (t + v4*256)*4;
    int bb = e >> 8, ss = e & 255;
    int base = ss*16 + ((((bb>>2) ^ ((ss>>2)&3))) << 2) + (bb&3);
    stT[base] = f.x; stT[base+16]=f.y; stT[base+32]=f.z; stT[base+48]=f.w;
  }
  __syncthreads();
  for (int pass=0; pass<3; ++pass){
    int c = pass*256 + t;
    if (c < XCOLS){
      float acc[16];
      #pragma unroll
      for (int i=0;i<16;++i) acc[i]=0.f;
      for (int s0=0;s0<STATED;s0+=16){
        #pragma unroll
        for (int ss=0;ss<16;++ss){
          int s = s0+ss;
          float w = WstT[s*XCOLS + c];
          const float4* row = reinterpret_cast<const float4*>(&stT[s*16]);
          #pragma unroll
          for (int m=0;m<4;++m){
            int bc = m ^ ((ss>>2)&3);
            float4 r = row[m];
            acc[bc*4+0]+=r.x*w; acc[bc*4+1]+=r.y*w; acc[bc*4+2]+=r.z*w; acc[bc*4+3]+=r.w*w;
          }
        }
      }
      if (c < 512){
        float bb = hb_b[c];
        #pragma unroll
        for (int i=0;i<16;++i) b_all[(size_t)(b0+i)*512 + c] = acc[i] + bb;
      } else if (c < 528){
        float bb = wn_b[c-512];
        #pragma unroll
        for (int i=0;i<16;++i) dis[(b0+i)*NAG + (c-512)] = fabsf(acc[i] + bb);
      } else {
        float bb = v1_b[c-528];
        #pragma unroll
        for (int i=0;i<16;++i) vh[i][c-528] = fmaxf(acc[i] + bb, 0.f);
      }
    }
  }
  __syncthreads();
  if (t < 16){
    float s = v2_b[0];
    #pragma unroll
    for (int e=0;e<32;++e) s += vh[t][e]*v2_w[e];
    vv[b0+t] = s;
  }
}

// ---------------- kernel 2: full dual-GAT + mixing, one block per batch ----------------
// LDS plan (39424 B total -> 4 blocks/CU):
//   arena1[2048 fl]: obsT (P1) -> o2f[576]@0 + prod[576]@1024
//   arena2[6176 fl]: WhA[16*258]@0 + attT[2048]@4128 -> xcatT[5120]@0
//                    -> zT[2560]@0 + zfT[2560]@2560 -> part[4096]@0
__global__ __launch_bounds__(256,4) void gat_kernel(
    const float* __restrict__ agent_qs,
    const float* __restrict__ obs_ls,
    const float* __restrict__ adj_ls,
    const float* __restrict__ g1_Wh, const float* __restrict__ g1_ah,
    const float* __restrict__ g1_Wout,
    const float* __restrict__ gf_Wh, const float* __restrict__ gf_ah,
    const float* __restrict__ gf_Wout,
    const float* __restrict__ wa_g,      // [4][128]
    const float* __restrict__ b_all_ws, const float* __restrict__ dis_ws,
    const float* __restrict__ vv_ws,
    float* __restrict__ out){
  __shared__ __align__(16) float arena1[2048];
  __shared__ __align__(16) float arena2[6176];
  __shared__ __align__(16) float adj_s[256];
  __shared__ float qs_s[16];
  __shared__ float u_s[128], v_s[128];
  __shared__ float u2_s[16], v2_s[16], u2f_s[16], v2f_s[16];
  __shared__ __align__(16) float att2T[256], att2Tf[256];
  __shared__ float hypwf[512];
  __shared__ float y_s[16];

  float* obsT  = arena1;
  float* o2f   = arena1;
  float* prod  = arena1 + 1024;   // stride 36
  float* WhA   = arena2;          // stride WST=258
  float* attT  = arena2 + 4128;   // [g][j][chunk-swz]
  float* xcatT = arena2;          // [col][row] stride 20
  float* zT    = arena2;          // [k][i] stride 20
  float* zfT   = arena2 + 2560;
  float* part  = arena2;          // [8][512]

  const int t = threadIdx.x;
  const int b = blockIdx.x;

  // ---- loads: obs transposed (chunk-swizzled), adj, qs ----
  {
    const float4* src = reinterpret_cast<const float4*>(obs_ls + (size_t)b*(NAG*OBSD));
    #pragma unroll
    for (int v4=0; v4<2; ++v4){
      float4 f = src[t + v4*256];
      int e = (t + v4*256)*4;
      int r = e >> 7, k = e & 127;
      int base = k*16 + ((((r>>2) ^ ((k>>2)&3))) << 2) + (r&3);
      obsT[base]    = f.x;
      obsT[base+16] = f.y;
      obsT[base+32] = f.z;
      obsT[base+48] = f.w;
    }
    if (t < 64) reinterpret_cast<float4*>(adj_s)[t] =
        reinterpret_cast<const float4*>(adj_ls + (size_t)b*256)[t];
    if (t < 16) qs_s[t] = agent_qs[b*NAG + t];
  }
  __syncthreads();

  // ---- Phase 1: Wh = obs @ W (8 head-instances) ----
  {
    int g = t >> 5, c = t & 31;
    const float* W = (g < 4) ? (g1_Wh + g*OBSD*32) : (gf_Wh + (g-4)*OBSD*32);
    float acc[16];
    #pragma unroll
    for (int i=0;i<16;++i) acc[i]=0.f;
    for (int k0=0;k0<OBSD;k0+=16){
      #pragma unroll
      for (int kk=0;kk<16;++kk){
        int k = k0+kk;
        float w = W[k*32 + c];
        const float4* row = reinterpret_cast<const float4*>(&obsT[k*16]);
        #pragma unroll
        for (int m=0;m<4;++m){
          int rc = m ^ ((kk>>2)&3);
          float4 r4 = row[m];
          acc[rc*4+0]+=r4.x*w; acc[rc*4+1]+=r4.y*w; acc[rc*4+2]+=r4.z*w; acc[rc*4+3]+=r4.w*w;
        }
      }
    }
    #pragma unroll
    for (int i=0;i<16;++i) WhA[i*WST + t] = acc[i];
  }
  __syncthreads();

  // ---- u,v per (head-instance, agent) ----
  {
    int g = t >> 5, i = (t >> 1) & 15, which = t & 1;
    const float* a = ((g < 4) ? (g1_ah + g*64) : (gf_ah + (g-4)*64)) + which*32;
    float s = 0.f;
    int base = i*WST + g*32;
    #pragma unroll
    for (int c=0;c<32;++c) s += WhA[base+c]*a[c];
    if (which == 0) u_s[g*16+i] = s; else v_s[g*16+i] = s;
  }
  __syncthreads();

  // ---- Phase 2: att = softmax_i(mask(lrelu(u_i+v_j))) -> attT swizzled ----
  if (t < 128){
    int g = t >> 4, j = t & 15;
    float vj = v_s[g*16+j];
    float ev[16]; float m = -INFINITY;
    #pragma unroll
    for (int i=0;i<16;++i){
      float x = lrelu(u_s[g*16+i] + vj);
      x = (adj_s[i*16+j] > 0.f) ? x : NEGV;
      ev[i]=x; m = fmaxf(m,x);
    }
    float ssum = 0.f;
    #pragma unroll
    for (int i=0;i<16;++i){ ev[i]=__expf(ev[i]-m); ssum+=ev[i]; }
    float inv = 1.f/ssum;
    #pragma unroll
    for (int i=0;i<16;++i) ev[i]*=inv;
    int sw = (j&3) ^ ((j>>2)&3);
    #pragma unroll
    for (int ic=0;ic<4;++ic){
      int m4 = ic ^ sw;
      *reinterpret_cast<float4*>(&attT[g*256 + j*16 + m4*4]) =
          make_float4(ev[ic*4], ev[ic*4+1], ev[ic*4+2], ev[ic*4+3]);
    }
  }
  __syncthreads();

  // ---- Phase 3: xcat = elu(att @ Wh) -> regs -> xcatT[col][row] ----
  {
    int g = t >> 5, c = t & 31;
    float acc[16];
    #pragma unroll
    for (int i=0;i<16;++i) acc[i]=0.f;
    #pragma unroll
    for (int j=0;j<16;++j){
      float w = WhA[j*WST + g*32 + c];
      int sw = (j&3) ^ ((j>>2)&3);
      const float4* row = reinterpret_cast<const float4*>(&attT[g*256 + j*16]);
      #pragma unroll
      for (int m=0;m<4;++m){
        int ic = m ^ sw;
        float4 r4 = row[m];
        acc[ic*4+0]+=r4.x*w; acc[ic*4+1]+=r4.y*w; acc[ic*4+2]+=r4.z*w; acc[ic*4+3]+=r4.w*w;
      }
    }
    #pragma unroll
    for (int i=0;i<16;++i) acc[i] = eluf(acc[i]);
    __syncthreads();   // arena2: WhA/attT -> xcatT
    #pragma unroll
    for (int q=0;q<4;++q)
      *reinterpret_cast<float4*>(&xcatT[t*XST + q*4]) =
          make_float4(acc[q*4], acc[q*4+1], acc[q*4+2], acc[q*4+3]);
  }
  __syncthreads();

  // ---- UV2: u2/v2 = xcat @ wa (precomputed Wout@a) ----
  if (t < 64){
    int vec = t >> 4, i = t & 15;
    const float* wa = wa_g + vec*128;
    int koff = (vec < 2) ? 0 : 128;
    float s = 0.f;
    for (int k=0;k<128;++k) s += xcatT[(koff+k)*XST + i]*wa[k];
    if (vec==0) u2_s[i]=s; else if (vec==1) v2_s[i]=s;
    else if (vec==2) u2f_s[i]=s; else v2f_s[i]=s;
  }
  __syncthreads();

  // ---- ATT2: both second-layer attentions ----
  if (t < 32){
    int side = t >> 4, j = t & 15;
    const float* uu = side ? u2f_s : u2_s;
    const float* vv = side ? v2f_s : v2_s;
    float* dst = side ? att2Tf : att2T;
    float vj = vv[j];
    float ev[16]; float m=-INFINITY;
    #pragma unroll
    for (int i=0;i<16;++i){
      float x = lrelu(uu[i]+vj);
      x = (adj_s[i*16+j] > 0.f) ? x : NEGV;
      ev[i]=x; m=fmaxf(m,x);
    }
    float ssum=0.f;
    #pragma unroll
    for (int i=0;i<16;++i){ ev[i]=__expf(ev[i]-m); ssum+=ev[i]; }
    float inv=1.f/ssum;
    #pragma unroll
    for (int i=0;i<16;++i) ev[i]*=inv;
    int sw = (j&3) ^ ((j>>2)&3);
    #pragma unroll
    for (int ic=0;ic<4;++ic){
      int m4 = ic ^ sw;
      *reinterpret_cast<float4*>(&dst[j*16 + m4*4]) =
          make_float4(ev[ic*4], ev[ic*4+1], ev[ic*4+2], ev[ic*4+3]);
    }
  }
  __syncthreads();

  // ---- Z: z = att2T^T-apply on xcat (both GATs), regs then store over xcatT ----
  {
    int k = t & 127, ih = t >> 7;   // rows ih*8..ih*8+7
    float4 xg[4], xf[4];
    const float4* colg = reinterpret_cast<const float4*>(&xcatT[k*XST]);
    const float4* colf = reinterpret_cast<const float4*>(&xcatT[(128+k)*XST]);
    #pragma unroll
    for (int q=0;q<4;++q){ xg[q]=colg[q]; xf[q]=colf[q]; }
    const float* xcg = reinterpret_cast<const float*>(xg);
    const float* xcf = reinterpret_cast<const float*>(xf);
    float z1[8], z2[8];
    #pragma unroll
    for (int i=0;i<8;++i){ z1[i]=0.f; z2[i]=0.f; }
    #pragma unroll
    for (int j=0;j<16;++j){
      int sw = (j&3) ^ ((j>>2)&3);
      float4 a0 = *reinterpret_cast<const float4*>(&att2T[j*16 + (((ih*2+0)^sw)<<2)]);
      float4 a1 = *reinterpret_cast<const float4*>(&att2T[j*16 + (((ih*2+1)^sw)<<2)]);
      float xj = xcg[j];
      z1[0]+=a0.x*xj; z1[1]+=a0.y*xj; z1[2]+=a0.z*xj; z1[3]+=a0.w*xj;
      z1[4]+=a1.x*xj; z1[5]+=a1.y*xj; z1[6]+=a1.z*xj; z1[7]+=a1.w*xj;
      float4 b0 = *reinterpret_cast<const float4*>(&att2Tf[j*16 + (((ih*2+0)^sw)<<2)]);
      float4 b1 = *reinterpret_cast<const float4*>(&att2Tf[j*16 + (((ih*2+1)^sw)<<2)]);
      float fj = xcf[j];
      z2[0]+=b0.x*fj; z2[1]+=b0.y*fj; z2[2]+=b0.z*fj; z2[3]+=b0.w*fj;
      z2[4]+=b1.x*fj; z2[5]+=b1.y*fj; z2[6]+=b1.z*fj; z2[7]+=b1.w*fj;
    }
    __syncthreads();   // all xcatT reads done before overwrite
    *reinterpret_cast<float4*>(&zT[k*XST + ih*8])      = make_float4(z1[0],z1[1],z1[2],z1[3]);
    *reinterpret_cast<float4*>(&zT[k*XST + ih*8 + 4])  = make_float4(z1[4],z1[5],z1[6],z1[7]);
    *reinterpret_cast<float4*>(&zfT[k*XST + ih*8])     = make_float4(z2[0],z2[1],z2[2],z2[3]);
    *reinterpret_cast<float4*>(&zfT[k*XST + ih*8 + 4]) = make_float4(z2[4],z2[5],z2[6],z2[7]);
  }
  __syncthreads();

  // ---- gf output GEMM: of = elu(zf @ gf_Wout) ----
  {
    int c = t & 31, ii = t >> 5;   // rows ii, ii+8
    float a0=0.f, a1=0.f;
    #pragma unroll 2
    for (int k=0;k<128;++k){
      float w = gf_Wout[k*32 + c];
      a0 += zfT[k*XST + ii]*w;
      a1 += zfT[k*XST + ii + 8]*w;
    }
    o2f[ii*36 + c]     = eluf(a0);
    o2f[(ii+8)*36 + c] = eluf(a1);
  }
  __syncthreads();
  if (t < 32){   // gf log_softmax over agents, abs -> hypwf
    int c = t;
    float m = -INFINITY;
    #pragma unroll
    for (int i=0;i<16;++i) m = fmaxf(m, o2f[i*36+c]);
    float ssum = 0.f;
    #pragma unroll
    for (int i=0;i<16;++i) ssum += __expf(o2f[i*36+c]-m);
    float ls = m + __logf(ssum);
    #pragma unroll
    for (int i=0;i<16;++i) hypwf[i*32+c] = fabsf(o2f[i*36+c]-ls);
  }

  // ---- g1 output GEMM: o = z @ g1_Wout, cols c0=t, c1=t+256; epilogue in regs ----
  {
    const int c0 = t, c1 = t+256;
    float acc0[16], acc1[16];
    #pragma unroll
    for (int i=0;i<16;++i){acc0[i]=0.f; acc1[i]=0.f;}
    #pragma unroll 2
    for (int k=0;k<128;++k){
      float w0 = g1_Wout[k*512 + c0];
      float w1 = g1_Wout[k*512 + c1];
      const float4* row = reinterpret_cast<const float4*>(&zT[k*XST]);
      #pragma unroll
      for (int q=0;q<4;++q){
        float4 r = row[q];
        acc0[q*4+0]+=r.x*w0; acc0[q*4+1]+=r.y*w0; acc0[q*4+2]+=r.z*w0; acc0[q*4+3]+=r.w*w0;
        acc1[q*4+0]+=r.x*w1; acc1[q*4+1]+=r.y*w1; acc1[q*4+2]+=r.z*w1; acc1[q*4+3]+=r.w*w1;
      }
    }
    float m0=-INFINITY, m1=-INFINITY;
    #pragma unroll
    for (int i=0;i<16;++i){
      acc0[i]=eluf(acc0[i]); acc1[i]=eluf(acc1[i]);
      m0=fmaxf(m0,acc0[i]); m1=fmaxf(m1,acc1[i]);
    }
    float s0=0.f, s1=0.f;
    #pragma unroll
    for (int i=0;i<16;++i){ s0+=__expf(acc0[i]-m0); s1+=__expf(acc1[i]-m1); }
    float ls0 = m0+__logf(s0), ls1 = m1+__logf(s1);
    int g = t >> 5, e = t & 31;   // c0 -> agent g, c1 -> agent 8+g
    float q0 = qs_s[g], q1 = qs_s[8+g];
    __syncthreads();   // all zT/zfT reads done before part overwrite
    #pragma unroll
    for (int i=0;i<16;++i)
      part[g*512 + i*32 + e] = q0*fabsf(acc0[i]-ls0) + q1*fabsf(acc1[i]-ls1);
  }
  __syncthreads();

  // ---- hidden = elu(sum_n qs_n*w1 + b_all); prod = hidden*hypwf ----
  {
    #pragma unroll
    for (int pp=0; pp<2; ++pp){
      int p = t + pp*256;
      float s = b_all_ws[(size_t)b*512 + p];
      #pragma unroll
      for (int g=0; g<8; ++g) s += part[g*512 + p];
      prod[(p>>5)*36 + (p&31)] = eluf(s) * hypwf[p];
    }
  }
  __syncthreads();
  if (t < 16){
    float s = 0.f;
    #pragma unroll
    for (int e=0;e<32;++e) s += prod[t*36+e];
    y_s[t] = s * dis_ws[b*NAG + t];
  }
  __syncthreads();
  if (t == 0){
    float q = vv_ws[b];
    #pragma unroll
    for (int j=0;j<16;++j) q += y_s[j];
    out[b] = q;
  }
}

extern "C" void kernel_launch(void* const* d_in, const int* in_sizes, int n_in,
                              void* d_out, int out_size, void* d_ws, size_t ws_size,
                              hipStream_t stream) {
  const float* agent_qs = (const float*)d_in[0];
  const float* states   = (const float*)d_in[1];
  const float* obs_ls   = (const float*)d_in[2];
  const float* adj_ls   = (const float*)d_in[3];
  const float* wn_w     = (const float*)d_in[4];
  const float* wn_b     = (const float*)d_in[5];
  const float* g1_Wh    = (const float*)d_in[6];
  const float* g1_ah    = (const float*)d_in[7];
  const float* g1_Wout  = (const float*)d_in[8];
  const float* g1_aout  = (const float*)d_in[9];
  const float* gf_Wh    = (const float*)d_in[10];
  const float* gf_ah    = (const float*)d_in[11];
  const float* gf_Wout  = (const float*)d_in[12];
  const float* gf_aout  = (const float*)d_in[13];
  const float* hb_W     = (const float*)d_in[14];
  const float* hb_b     = (const float*)d_in[15];
  const float* v1_w     = (const float*)d_in[16];
  const float* v1_b     = (const float*)d_in[17];
  const float* v2_w     = (const float*)d_in[18];
  const float* v2_b     = (const float*)d_in[19];

  float* ws    = (float*)d_ws;
  float* WstT  = ws;                        // 256*560
  float* b_all = WstT + STATED*XCOLS;       // 8192*512
  float* dis   = b_all + (size_t)BTOT*512;  // 8192*16
  float* vvv   = dis + (size_t)BTOT*NAG;    // 8192
  float* wa    = vvv + BTOT;                // 4*128

  prep_kernel<<<dim3((STATED*XCOLS + 255)/256), dim3(256), 0, stream>>>(hb_W, wn_w, v1_w, WstT);
  prep2_kernel<<<dim3(1), dim3(128), 0, stream>>>(g1_Wout, g1_aout, gf_Wout, gf_aout, wa);
  st_kernel<<<dim3(BTOT/16), dim3(256), 0, stream>>>(states, WstT, hb_b, wn_b, v1_b, v2_w, v2_b,
                                                     b_all, dis, vvv);
  gat_kernel<<<dim3(BTOT), dim3(256), 0, stream>>>(agent_qs, obs_ls, adj_ls,
                                                   g1_Wh, g1_ah, g1_Wout,
                                                   gf_Wh, gf_ah, gf_Wout,
                                                   wa, b_all, dis, vvv, (float*)d_out);
}

// Round 3
// 218.847 us; speedup vs baseline: 4.0740x; 2.6886x over previous
//
#include <hip/hip_runtime.h>
#include <math.h>

#define NAG 16
#define OBSD 128
#define STATED 256
#define ALPHA 0.2f
#define NEGV -9.0e15f
#define BTOT 8192
#define XCOLS 560   // 512 b_all + 16 dis + 32 v1

typedef _Float16 v4h __attribute__((ext_vector_type(4)));
typedef _Float16 v8h __attribute__((ext_vector_type(8)));
typedef float v4f __attribute__((ext_vector_type(4)));

__device__ __forceinline__ float lrelu(float x){ return x > 0.f ? x : ALPHA*x; }
__device__ __forceinline__ float eluf(float x){ return x > 0.f ? x : (__expf(x)-1.f); }

#define MFMA16(A,B,C) __builtin_amdgcn_mfma_f32_16x16x16f16((A),(B),(C),0,0,0)
#define MFMA32(A,B,C) __builtin_amdgcn_mfma_f32_16x16x32_f16((A),(B),(C),0,0,0)

// ---------------- prep: WstT[s][c] = fused state-side weight, transposed ----------------
__global__ void prep_kernel(const float* __restrict__ hb_W,
                            const float* __restrict__ wn_w,
                            const float* __restrict__ v1_w,
                            float* __restrict__ WstT){
  int idx = blockIdx.x*256 + threadIdx.x;
  if (idx >= STATED*XCOLS) return;
  int s = idx / XCOLS, c = idx - s*XCOLS;
  float v;
  if (c < 512)      v = hb_W[c*STATED + s];
  else if (c < 528) v = wn_w[(c-512)*STATED + s];
  else              v = v1_w[(c-528)*STATED + s];
  WstT[idx] = v;
}

// ---------------- prep2: wa[4][128] = Wout @ aout halves ----------------
__global__ void prep2_kernel(const float* __restrict__ g1_Wout, const float* __restrict__ g1_aout,
                             const float* __restrict__ gf_Wout, const float* __restrict__ gf_aout,
                             float* __restrict__ wa){
  int k = threadIdx.x;  // 128
  float su = 0.f, sv = 0.f;
  for (int c = 0; c < 512; ++c){
    float w = g1_Wout[k*512 + c];
    su += w * g1_aout[c];
    sv += w * g1_aout[512 + c];
  }
  wa[k] = su; wa[128 + k] = sv;
  float fu = 0.f, fv = 0.f;
  for (int c = 0; c < 32; ++c){
    float w = gf_Wout[k*32 + c];
    fu += w * gf_aout[c];
    fv += w * gf_aout[32 + c];
  }
  wa[256 + k] = fu; wa[384 + k] = fv;
}

// ---------------- pack first-layer weights into f16 MFMA B-frag order ----------------
// dst[nt 0..15][kk 0..3][lane 0..63][j 0..7]: B[k][n]: k=kk*32+(lane>>4)*8+j, head g=nt>>1
__global__ void pack_wh_kernel(const float* __restrict__ g1_Wh, const float* __restrict__ gf_Wh,
                               _Float16* __restrict__ dst){
  int idx = blockIdx.x*256 + threadIdx.x;   // 32768 total
  int j = idx & 7, lane = (idx>>3)&63, kk = (idx>>9)&3, nt = idx>>11;
  int k = kk*32 + (lane>>4)*8 + j;
  int g = nt>>1, cih = (nt&1)*16 + (lane&15);
  float v = (g<4) ? g1_Wh[(g*OBSD + k)*32 + cih] : gf_Wh[((g-4)*OBSD + k)*32 + cih];
  dst[idx] = (_Float16)v;
}

// ---------------- pack second-layer weights (g1: 32 ntiles, gf: 2 ntiles) ----------------
__global__ void pack_wout_kernel(const float* __restrict__ g1_Wout, const float* __restrict__ gf_Wout,
                                 _Float16* __restrict__ dst1, _Float16* __restrict__ dstf){
  int idx = blockIdx.x*256 + threadIdx.x;   // 69632 total
  if (idx < 65536){
    int j = idx&7, lane=(idx>>3)&63, kk=(idx>>9)&3, nt=idx>>11;
    int k = kk*32 + (lane>>4)*8 + j;
    dst1[idx] = (_Float16)g1_Wout[k*512 + nt*16 + (lane&15)];
  } else {
    int i2 = idx - 65536;
    int j=i2&7, lane=(i2>>3)&63, kk=(i2>>9)&3, nt=i2>>11;
    int k = kk*32 + (lane>>4)*8 + j;
    dstf[i2] = (_Float16)gf_Wout[k*32 + nt*16 + (lane&15)];
  }
}

// ---------------- kernel 1: per-batch state projections (unchanged) ----------------
__global__ __launch_bounds__(256) void st_kernel(
    const float* __restrict__ states,
    const float* __restrict__ WstT,
    const float* __restrict__ hb_b,
    const float* __restrict__ wn_b,
    const float* __restrict__ v1_b,
    const float* __restrict__ v2_w,
    const float* __restrict__ v2_b,
    float* __restrict__ b_all,
    float* __restrict__ dis,
    float* __restrict__ vv){
  __shared__ __align__(16) float stT[STATED*16];
  __shared__ float vh[16][32];
  const int t = threadIdx.x;
  const int b0 = blockIdx.x*16;
  const float4* src = reinterpret_cast<const float4*>(states + (size_t)b0*STATED);
  #pragma unroll
  for (int v4=0; v4<4; ++v4){
    float4 f = src[t + v4*256];
    int e = (t + v4*256)*4;
    int bb = e >> 8, ss = e & 255;
    int base = ss*16 + ((((bb>>2) ^ ((ss>>2)&3))) << 2) + (bb&3);
    stT[base] = f.x; stT[base+16]=f.y; stT[base+32]=f.z; stT[base+48]=f.w;
  }
  __syncthreads();
  for (int pass=0; pass<3; ++pass){
    int c = pass*256 + t;
    if (c < XCOLS){
      float acc[16];
      #pragma unroll
      for (int i=0;i<16;++i) acc[i]=0.f;
      for (int s0=0;s0<STATED;s0+=16){
        #pragma unroll
        for (int ss=0;ss<16;++ss){
          int s = s0+ss;
          float w = WstT[s*XCOLS + c];
          const float4* row = reinterpret_cast<const float4*>(&stT[s*16]);
          #pragma unroll
          for (int m=0;m<4;++m){
            int bc = m ^ ((ss>>2)&3);
            float4 r = row[m];
            acc[bc*4+0]+=r.x*w; acc[bc*4+1]+=r.y*w; acc[bc*4+2]+=r.z*w; acc[bc*4+3]+=r.w*w;
          }
        }
      }
      if (c < 512){
        float bb = hb_b[c];
        #pragma unroll
        for (int i=0;i<16;++i) b_all[(size_t)(b0+i)*512 + c] = acc[i] + bb;
      } else if (c < 528){
        float bb = wn_b[c-512];
        #pragma unroll
        for (int i=0;i<16;++i) dis[(b0+i)*NAG + (c-512)] = fabsf(acc[i] + bb);
      } else {
        float bb = v1_b[c-528];
        #pragma unroll
        for (int i=0;i<16;++i) vh[i][c-528] = fmaxf(acc[i] + bb, 0.f);
      }
    }
  }
  __syncthreads();
  if (t < 16){
    float s = v2_b[0];
    #pragma unroll
    for (int e=0;e<32;++e) s += vh[t][e]*v2_w[e];
    vv[b0+t] = s;
  }
}

// ---------------- kernel 2: dual-GAT via MFMA, one block per batch ----------------
__global__ __launch_bounds__(256,4) void gat_kernel(
    const float* __restrict__ agent_qs,
    const float* __restrict__ obs_ls,
    const float* __restrict__ adj_ls,
    const float* __restrict__ g1_ah,
    const float* __restrict__ gf_ah,
    const _Float16* __restrict__ whf,    // [16][4][64][8]
    const _Float16* __restrict__ wo1f,   // [32][4][64][8]
    const _Float16* __restrict__ wodf,   // [2][4][64][8]
    const float* __restrict__ wa_g,      // [4][128]
    const float* __restrict__ b_all_ws,
    const float* __restrict__ dis_ws,
    const float* __restrict__ vv_ws,
    float* __restrict__ out){
  __shared__ __align__(16) float arena[2304];   // att_s(8*280) / z halves(4096h) / part(4*576)
  __shared__ __align__(16) float att2_s[560];   // att2 (stride 17) -> prod (stride 33)
  __shared__ float hypwf[512];
  __shared__ float uv_s[256];                   // u[128],v[128] -> red[128]
  __shared__ float u2v2[64];
  __shared__ __align__(16) float adj_s[256];
  __shared__ float qs_s[16];
  __shared__ float y_s[16];

  const int t = threadIdx.x;
  const int b = blockIdx.x;
  const int w = t >> 6;
  const int lane = t & 63;
  const int lg = lane >> 4, li = lane & 15;
  const int sideW = w >> 1;   // 0: g1 (waves 0,1), 1: gf (waves 2,3)

  if (t < 64) reinterpret_cast<float4*>(adj_s)[t] =
      reinterpret_cast<const float4*>(adj_ls + (size_t)b*256)[t];
  if (t >= 64 && t < 80) qs_s[t-64] = agent_qs[b*NAG + (t-64)];

  // ---- P1: Wh = obs @ Wcat  (A = obs direct from global, B = prepacked frags) ----
  const float* ob = obs_ls + (size_t)b*(NAG*OBSD) + li*OBSD + lg*8;
  v8h aob[4];
  #pragma unroll
  for (int kk=0;kk<4;++kk){
    v4f f0 = *reinterpret_cast<const v4f*>(ob + kk*32);
    v4f f1 = *reinterpret_cast<const v4f*>(ob + kk*32 + 4);
    v8h h;
    #pragma unroll
    for (int j=0;j<4;++j){ h[j] = (_Float16)f0[j]; h[4+j] = (_Float16)f1[j]; }
    aob[kk] = h;
  }
  v4f whD[4];
  #pragma unroll
  for (int n=0;n<4;++n) whD[n] = (v4f){0.f,0.f,0.f,0.f};
  #pragma unroll
  for (int n=0;n<4;++n){
    int nt = w*4 + n;
    #pragma unroll
    for (int kk=0;kk<4;++kk){
      v8h bf = *reinterpret_cast<const v8h*>(whf + (size_t)((nt*4+kk)*64 + lane)*8);
      whD[n] = MFMA32(aob[kk], bf, whD[n]);
    }
  }

  // ---- u,v: per-head dot with a-vectors, 16-lane shuffle reduce ----
  {
    float pu[2][4], pv[2][4];
    #pragma unroll
    for (int hh=0;hh<2;++hh)
      #pragma unroll
      for (int r=0;r<4;++r){ pu[hh][r]=0.f; pv[hh][r]=0.f; }
    #pragma unroll
    for (int n=0;n<4;++n){
      int g = w*2 + (n>>1);
      const float* ah = (g<4)? (g1_ah + g*64) : (gf_ah + (g-4)*64);
      float a1 = ah[(n&1)*16 + li];
      float a2 = ah[32 + (n&1)*16 + li];
      #pragma unroll
      for (int r=0;r<4;++r){ pu[n>>1][r] += whD[n][r]*a1; pv[n>>1][r] += whD[n][r]*a2; }
    }
    #pragma unroll
    for (int off=1; off<16; off<<=1){
      #pragma unroll
      for (int hh=0;hh<2;++hh)
        #pragma unroll
        for (int r=0;r<4;++r){
          pu[hh][r] += __shfl_xor(pu[hh][r], off, 64);
          pv[hh][r] += __shfl_xor(pv[hh][r], off, 64);
        }
    }
    if (li == 0){
      #pragma unroll
      for (int hh=0;hh<2;++hh)
        #pragma unroll
        for (int r=0;r<4;++r){
          uv_s[(w*2+hh)*16 + lg*4 + r]       = pu[hh][r];
          uv_s[128 + (w*2+hh)*16 + lg*4 + r] = pv[hh][r];
        }
    }
  }

  // Wh D-frag -> f16 B-frag for P3 (D layout == B layout)
  v4h whB[4];
  #pragma unroll
  for (int n=0;n<4;++n)
    #pragma unroll
    for (int r=0;r<4;++r) whB[n][r] = (_Float16)whD[n][r];

  __syncthreads();

  // ---- P2: att = softmax_i(mask(lrelu(u_i+v_j))) -> att_s[g][j][i] (stride 17) ----
  if (t < 128){
    int g = t >> 4, j = t & 15;
    float vj = uv_s[128 + g*16 + j];
    float ev[16]; float m = -INFINITY;
    #pragma unroll
    for (int i=0;i<16;++i){
      float x = lrelu(uv_s[g*16+i] + vj);
      x = (adj_s[i*16+j] > 0.f) ? x : NEGV;
      ev[i]=x; m = fmaxf(m,x);
    }
    float ssum = 0.f;
    #pragma unroll
    for (int i=0;i<16;++i){ ev[i]=__expf(ev[i]-m); ssum+=ev[i]; }
    float inv = 1.f/ssum;
    #pragma unroll
    for (int i=0;i<16;++i) arena[g*280 + j*17 + i] = ev[i]*inv;
  }
  __syncthreads();

  // ---- P3: xcat = elu(att @ Wh); A = att (LDS), B = whB (regs) ----
  v4f xcD[4];
  #pragma unroll
  for (int n=0;n<4;++n) xcD[n] = (v4f){0.f,0.f,0.f,0.f};
  #pragma unroll
  for (int hh=0;hh<2;++hh){
    int g = w*2+hh;
    v4h afr;
    #pragma unroll
    for (int jj=0;jj<4;++jj) afr[jj] = (_Float16)arena[g*280 + (lg*4+jj)*17 + li];
    xcD[hh*2]   = MFMA16(afr, whB[hh*2],   xcD[hh*2]);
    xcD[hh*2+1] = MFMA16(afr, whB[hh*2+1], xcD[hh*2+1]);
  }
  v4h xcB[4];
  #pragma unroll
  for (int n=0;n<4;++n)
    #pragma unroll
    for (int r=0;r<4;++r){
      float e = eluf(xcD[n][r]);
      xcD[n][r] = e;
      xcB[n][r] = (_Float16)e;
    }

  // ---- u2/v2 partials: xcat @ wa, shuffle reduce, red into uv_s ----
  {
    float p2u[4] = {0.f,0.f,0.f,0.f}, p2v[4] = {0.f,0.f,0.f,0.f};
    #pragma unroll
    for (int n=0;n<4;++n){
      int cl = ((w&1)*4 + n)*16 + li;
      float wu = wa_g[sideW*256 + cl];
      float wv = wa_g[sideW*256 + 128 + cl];
      #pragma unroll
      for (int r=0;r<4;++r){ p2u[r] += xcD[n][r]*wu; p2v[r] += xcD[n][r]*wv; }
    }
    #pragma unroll
    for (int off=1; off<16; off<<=1){
      #pragma unroll
      for (int r=0;r<4;++r){
        p2u[r] += __shfl_xor(p2u[r], off, 64);
        p2v[r] += __shfl_xor(p2v[r], off, 64);
      }
    }
    __syncthreads();   // all P2 readers of uv_s done? (they were done before P3's barrier) -- this
                       // barrier orders att_s reads (P3) before z writes AND publishes red below
    if (li == 0){
      #pragma unroll
      for (int r=0;r<4;++r){
        uv_s[w*32 + lg*4 + r]      = p2u[r];
        uv_s[w*32 + 16 + lg*4 + r] = p2v[r];
      }
    }
  }
  __syncthreads();

  // ---- UV2 combine across wave pairs ----
  if (t < 64){
    int side = t>>5, uvv = (t>>4)&1, i = t&15;
    u2v2[side*32 + uvv*16 + i] =
        uv_s[(side*2)*32 + uvv*16 + i] + uv_s[(side*2+1)*32 + uvv*16 + i];
  }
  __syncthreads();

  // ---- ATT2: both second-layer attentions -> att2_s[side][j][i] (stride 17) ----
  if (t < 32){
    int side = t>>4, j = t&15;
    float vj = u2v2[side*32 + 16 + j];
    float ev[16]; float m=-INFINITY;
    #pragma unroll
    for (int i=0;i<16;++i){
      float x = lrelu(u2v2[side*32 + i] + vj);
      x = (adj_s[i*16+j] > 0.f) ? x : NEGV;
      ev[i]=x; m=fmaxf(m,x);
    }
    float ssum=0.f;
    #pragma unroll
    for (int i=0;i<16;++i){ ev[i]=__expf(ev[i]-m); ssum+=ev[i]; }
    float inv=1.f/ssum;
    #pragma unroll
    for (int i=0;i<16;++i) att2_s[side*280 + j*17 + i] = ev[i]*inv;
  }
  __syncthreads();

  // ---- Z: z^T = xcat^T @ att2^T  (A = xcB regs, B = att2 from LDS); pack to zh ----
  _Float16* zh = reinterpret_cast<_Float16*>(arena);
  {
    v4h bat;
    #pragma unroll
    for (int jj=0;jj<4;++jj) bat[jj] = (_Float16)att2_s[sideW*280 + (lg*4+jj)*17 + li];
    #pragma unroll
    for (int n=0;n<4;++n){
      v4f zD = (v4f){0.f,0.f,0.f,0.f};
      zD = MFMA16(xcB[n], bat, zD);
      int ct = (w&1)*4 + n;
      int kk = ct>>1;
      int lp = li + 16*((ct&1)*2 + (lg>>1));
      _Float16* dst = zh + sideW*2048 + kk*512 + lp*8 + (lg&1)*4;
      union { unsigned int u; _Float16 h[2]; } q0, q1;
      q0.h[0]=(_Float16)zD[0]; q0.h[1]=(_Float16)zD[1];
      q1.h[0]=(_Float16)zD[2]; q1.h[1]=(_Float16)zD[3];
      *reinterpret_cast<unsigned int*>(dst)     = q0.u;
      *reinterpret_cast<unsigned int*>(dst + 2) = q1.u;
    }
  }
  __syncthreads();

  // ---- O: out-GEMMs. A-frags from zh, then barrier frees arena for part ----
  v8h az1[4], azf[4];
  #pragma unroll
  for (int kk=0;kk<4;++kk){
    az1[kk] = *reinterpret_cast<const v8h*>(zh + kk*512 + lane*8);
    azf[kk] = *reinterpret_cast<const v8h*>(zh + 2048 + kk*512 + lane*8);
  }
  __syncthreads();

  v4f oD[8];
  #pragma unroll
  for (int n=0;n<8;++n) oD[n] = (v4f){0.f,0.f,0.f,0.f};
  #pragma unroll
  for (int n=0;n<8;++n){
    int nt = w*8 + n;
    #pragma unroll
    for (int kk=0;kk<4;++kk){
      v8h bf = *reinterpret_cast<const v8h*>(wo1f + (size_t)((nt*4+kk)*64 + lane)*8);
      oD[n] = MFMA32(az1[kk], bf, oD[n]);
    }
  }
  v4f ofD = (v4f){0.f,0.f,0.f,0.f};
  if (w < 2){
    #pragma unroll
    for (int kk=0;kk<4;++kk){
      v8h bf = *reinterpret_cast<const v8h*>(wodf + (size_t)((w*4+kk)*64 + lane)*8);
      ofD = MFMA32(azf[kk], bf, ofD);
    }
  }

  // ---- g1 epilogue: elu -> col log_softmax over agents -> abs -> qs-weighted part ----
  {
    float pa0[4] = {0.f,0.f,0.f,0.f}, pa1[4] = {0.f,0.f,0.f,0.f};
    #pragma unroll
    for (int n=0;n<8;++n){
      float x0=eluf(oD[n][0]), x1=eluf(oD[n][1]), x2=eluf(oD[n][2]), x3=eluf(oD[n][3]);
      float m = fmaxf(fmaxf(x0,x1), fmaxf(x2,x3));
      m = fmaxf(m, __shfl_xor(m,16,64));
      m = fmaxf(m, __shfl_xor(m,32,64));
      float s = __expf(x0-m)+__expf(x1-m)+__expf(x2-m)+__expf(x3-m);
      s += __shfl_xor(s,16,64);
      s += __shfl_xor(s,32,64);
      float ls = m + __logf(s);
      float q = qs_s[w*4 + (n>>1)];
      if ((n&1)==0){
        pa0[0]+=q*fabsf(x0-ls); pa0[1]+=q*fabsf(x1-ls); pa0[2]+=q*fabsf(x2-ls); pa0[3]+=q*fabsf(x3-ls);
      } else {
        pa1[0]+=q*fabsf(x0-ls); pa1[1]+=q*fabsf(x1-ls); pa1[2]+=q*fabsf(x2-ls); pa1[3]+=q*fabsf(x3-ls);
      }
    }
    float* part = arena;
    #pragma unroll
    for (int r=0;r<4;++r){
      part[w*576 + (lg*4+r)*36 + li]      = pa0[r];
      part[w*576 + (lg*4+r)*36 + 16 + li] = pa1[r];
    }
  }
  // ---- gf epilogue -> hypwf ----
  if (w < 2){
    float x0=eluf(ofD[0]), x1=eluf(ofD[1]), x2=eluf(ofD[2]), x3=eluf(ofD[3]);
    float m = fmaxf(fmaxf(x0,x1), fmaxf(x2,x3));
    m = fmaxf(m, __shfl_xor(m,16,64));
    m = fmaxf(m, __shfl_xor(m,32,64));
    float s = __expf(x0-m)+__expf(x1-m)+__expf(x2-m)+__expf(x3-m);
    s += __shfl_xor(s,16,64);
    s += __shfl_xor(s,32,64);
    float ls = m + __logf(s);
    hypwf[(lg*4+0)*32 + w*16 + li] = fabsf(x0-ls);
    hypwf[(lg*4+1)*32 + w*16 + li] = fabsf(x1-ls);
    hypwf[(lg*4+2)*32 + w*16 + li] = fabsf(x2-ls);
    hypwf[(lg*4+3)*32 + w*16 + li] = fabsf(x3-ls);
  }
  __syncthreads();

  // ---- hidden = elu(sum part + b_all) * hypwf -> prod; reduce ----
  {
    float* prod = att2_s;   // stride 33
    #pragma unroll
    for (int pp=0;pp<2;++pp){
      int p = t + pp*256;
      int i = p>>5, e = p&31;
      float s = b_all_ws[(size_t)b*512 + p];
      #pragma unroll
      for (int wv=0;wv<4;++wv) s += arena[wv*576 + i*36 + e];
      prod[i*33 + e] = eluf(s) * hypwf[p];
    }
  }
  __syncthreads();
  if (t < 16){
    float s = 0.f;
    #pragma unroll
    for (int e=0;e<32;++e) s += att2_s[t*33+e];
    y_s[t] = s * dis_ws[b*NAG + t];
  }
  __syncthreads();
  if (t == 0){
    float q = vv_ws[b];
    #pragma unroll
    for (int j=0;j<16;++j) q += y_s[j];
    out[b] = q;
  }
}

extern "C" void kernel_launch(void* const* d_in, const int* in_sizes, int n_in,
                              void* d_out, int out_size, void* d_ws, size_t ws_size,
                              hipStream_t stream) {
  const float* agent_qs = (const float*)d_in[0];
  const float* states   = (const float*)d_in[1];
  const float* obs_ls   = (const float*)d_in[2];
  const float* adj_ls   = (const float*)d_in[3];
  const float* wn_w     = (const float*)d_in[4];
  const float* wn_b     = (const float*)d_in[5];
  const float* g1_Wh    = (const float*)d_in[6];
  const float* g1_ah    = (const float*)d_in[7];
  const float* g1_Wout  = (const float*)d_in[8];
  const float* g1_aout  = (const float*)d_in[9];
  const float* gf_Wh    = (const float*)d_in[10];
  const float* gf_ah    = (const float*)d_in[11];
  const float* gf_Wout  = (const float*)d_in[12];
  const float* gf_aout  = (const float*)d_in[13];
  const float* hb_W     = (const float*)d_in[14];
  const float* hb_b     = (const float*)d_in[15];
  const float* v1_w     = (const float*)d_in[16];
  const float* v1_b     = (const float*)d_in[17];
  const float* v2_w     = (const float*)d_in[18];
  const float* v2_b     = (const float*)d_in[19];

  float* ws    = (float*)d_ws;
  float* WstT  = ws;                        // 256*560 = 143360
  float* b_all = WstT + STATED*XCOLS;       // 8192*512
  float* dis   = b_all + (size_t)BTOT*512;  // 8192*16
  float* vvv   = dis + (size_t)BTOT*NAG;    // 8192
  float* wa    = vvv + BTOT;                // 512
  _Float16* whf  = (_Float16*)(wa + 512);   // 32768 halves
  _Float16* wo1f = whf + 32768;             // 65536 halves
  _Float16* wodf = wo1f + 65536;            // 4096 halves

  prep_kernel<<<dim3((STATED*XCOLS + 255)/256), dim3(256), 0, stream>>>(hb_W, wn_w, v1_w, WstT);
  prep2_kernel<<<dim3(1), dim3(128), 0, stream>>>(g1_Wout, g1_aout, gf_Wout, gf_aout, wa);
  pack_wh_kernel<<<dim3(128), dim3(256), 0, stream>>>(g1_Wh, gf_Wh, whf);
  pack_wout_kernel<<<dim3(272), dim3(256), 0, stream>>>(g1_Wout, gf_Wout, wo1f, wodf);
  st_kernel<<<dim3(BTOT/16), dim3(256), 0, stream>>>(states, WstT, hb_b, wn_b, v1_b, v2_w, v2_b,
                                                     b_all, dis, vvv);
  gat_kernel<<<dim3(BTOT), dim3(256), 0, stream>>>(agent_qs, obs_ls, adj_ls,
                                                   g1_ah, gf_ah, whf, wo1f, wodf,
                                                   wa, b_all, dis, vvv, (float*)d_out);
}

// Round 5
// 134.062 us; speedup vs baseline: 6.6505x; 1.6324x over previous
//
#include <hip/hip_runtime.h>
#include <math.h>

#define NAG 16
#define OBSD 128
#define STATED 256
#define ALPHA 0.2f
#define NEGV -9.0e15f
#define BTOT 8192

typedef _Float16 v4h __attribute__((ext_vector_type(4)));
typedef _Float16 v8h __attribute__((ext_vector_type(8)));
typedef float v4f __attribute__((ext_vector_type(4)));

__device__ __forceinline__ float lrelu(float x){ return x > 0.f ? x : ALPHA*x; }
__device__ __forceinline__ float eluf(float x){ return x > 0.f ? x : (__expf(x)-1.f); }

#define MFMA16(A,B,C) __builtin_amdgcn_mfma_f32_16x16x16f16((A),(B),(C),0,0,0)
#define MFMA32(A,B,C) __builtin_amdgcn_mfma_f32_16x16x32_f16((A),(B),(C),0,0,0)

// ---- prep2: wa[4][128] = Wout @ aout halves (g1 u/v, gf u/v) ----
__global__ void prep2_kernel(const float* __restrict__ g1_Wout, const float* __restrict__ g1_aout,
                             const float* __restrict__ gf_Wout, const float* __restrict__ gf_aout,
                             float* __restrict__ wa){
  int k = threadIdx.x;  // 128
  float su = 0.f, sv = 0.f;
  for (int c = 0; c < 512; ++c){
    float w = g1_Wout[k*512 + c];
    su += w * g1_aout[c];
    sv += w * g1_aout[512 + c];
  }
  wa[k] = su; wa[128 + k] = sv;
  float fu = 0.f, fv = 0.f;
  for (int c = 0; c < 32; ++c){
    float w = gf_Wout[k*32 + c];
    fu += w * gf_aout[c];
    fv += w * gf_aout[32 + c];
  }
  wa[256 + k] = fu; wa[384 + k] = fv;
}

// ---- pack first-layer weights + (W@a) u/v columns: whf [17][4][64][8] ----
__global__ void pack_wh_kernel(const float* __restrict__ g1_Wh, const float* __restrict__ gf_Wh,
                               const float* __restrict__ g1_ah, const float* __restrict__ gf_ah,
                               _Float16* __restrict__ dst){
  int idx = blockIdx.x*256 + threadIdx.x;   // 34816 total
  if (idx >= 17*2048) return;
  int j = idx & 7, lane = (idx>>3)&63, kk = (idx>>9)&3, nt = idx>>11;
  int k = kk*32 + (lane>>4)*8 + j;
  int li = lane & 15;
  float v;
  if (nt < 16){
    int g = nt>>1, c = (nt&1)*16 + li;
    v = (g<4) ? g1_Wh[(g*OBSD + k)*32 + c] : gf_Wh[((g-4)*OBSD + k)*32 + c];
  } else {
    int g = li>>1, half = li&1;
    const float* W = (g<4)? (g1_Wh + g*OBSD*32) : (gf_Wh + (g-4)*OBSD*32);
    const float* a = ((g<4)? (g1_ah + g*64) : (gf_ah + (g-4)*64)) + half*32;
    float s = 0.f;
    for (int c=0;c<32;++c) s += W[k*32+c]*a[c];
    v = s;
  }
  dst[idx] = (_Float16)v;
}

// ---- pack second-layer weights (g1: 32 ntiles, gf: 2 ntiles) ----
__global__ void pack_wout_kernel(const float* __restrict__ g1_Wout, const float* __restrict__ gf_Wout,
                                 _Float16* __restrict__ dst1, _Float16* __restrict__ dstf){
  int idx = blockIdx.x*256 + threadIdx.x;   // 69632 total
  if (idx < 65536){
    int j = idx&7, lane=(idx>>3)&63, kk=(idx>>9)&3, nt=idx>>11;
    int k = kk*32 + (lane>>4)*8 + j;
    dst1[idx] = (_Float16)g1_Wout[k*512 + nt*16 + (lane&15)];
  } else {
    int i2 = idx - 65536;
    int j=i2&7, lane=(i2>>3)&63, kk=(i2>>9)&3, nt=i2>>11;
    int k = kk*32 + (lane>>4)*8 + j;
    dstf[i2] = (_Float16)gf_Wout[k*32 + nt*16 + (lane&15)];
  }
}

// ---- pack state-side fused weights: wstf [35][8][64][8] ----
__global__ void pack_wst_kernel(const float* __restrict__ hb_W, const float* __restrict__ wn_w,
                                const float* __restrict__ v1_w, _Float16* __restrict__ dst){
  int idx = blockIdx.x*256 + threadIdx.x;
  if (idx >= 35*4096) return;
  int j = idx&7, lane=(idx>>3)&63, kk=(idx>>9)&7, nt=idx>>12;
  int s = kk*32 + (lane>>4)*8 + j;
  int c = nt*16 + (lane&15);
  float v;
  if (c < 512)      v = hb_W[c*STATED + s];
  else if (c < 528) v = wn_w[(c-512)*STATED + s];
  else              v = v1_w[(c-528)*STATED + s];
  dst[idx] = (_Float16)v;
}

// ---- kernel 1: state projections via MFMA (b_all, dis, V) ----
__global__ __launch_bounds__(256) void st_kernel(
    const float* __restrict__ states,
    const _Float16* __restrict__ wstf,
    const float* __restrict__ hb_b, const float* __restrict__ wn_b,
    const float* __restrict__ v1_b, const float* __restrict__ v2_w,
    const float* __restrict__ v2_b,
    float* __restrict__ b_all, float* __restrict__ dis, float* __restrict__ vv){
  __shared__ float vh_s[16*32];
  const int t = threadIdx.x, w = t>>6, lane = t&63, lg = lane>>4, li = lane&15;
  const int b0 = blockIdx.x*16;
  const float* sp = states + (size_t)(b0+li)*STATED + lg*8;
  v8h ast[8];
  #pragma unroll
  for (int kk=0;kk<8;++kk){
    v4f f0 = *reinterpret_cast<const v4f*>(sp + kk*32);
    v4f f1 = *reinterpret_cast<const v4f*>(sp + kk*32 + 4);
    v8h h;
    #pragma unroll
    for (int jj=0;jj<4;++jj){ h[jj]=(_Float16)f0[jj]; h[4+jj]=(_Float16)f1[jj]; }
    ast[kk]=h;
  }
  for (int nt=w; nt<35; nt+=4){
    v4f d = {0.f,0.f,0.f,0.f};
    #pragma unroll
    for (int kk=0;kk<8;++kk){
      v8h bf = *reinterpret_cast<const v8h*>(wstf + (size_t)(((nt*8+kk)<<6)+lane)*8);
      d = MFMA32(ast[kk], bf, d);
    }
    int c = nt*16 + li;
    if (c < 512){
      float bias = hb_b[c];
      #pragma unroll
      for (int r=0;r<4;++r) b_all[(size_t)(b0+lg*4+r)*512 + c] = d[r]+bias;
    } else if (c < 528){
      float bias = wn_b[c-512];
      #pragma unroll
      for (int r=0;r<4;++r) dis[(b0+lg*4+r)*NAG + (c-512)] = fabsf(d[r]+bias);
    } else {
      float bias = v1_b[c-528];
      #pragma unroll
      for (int r=0;r<4;++r) vh_s[(lg*4+r)*32 + (c-528)] = fmaxf(d[r]+bias, 0.f);
    }
  }
  __syncthreads();
  if (t < 16){
    float s = v2_b[0];
    #pragma unroll
    for (int e=0;e<32;++e) s += vh_s[t*32+e]*v2_w[e];
    vv[b0+t] = s;
  }
}

// ---- kernel 2: dual-GAT, wave-owns-batch (4 batches/block), joint out-GEMM ----
__global__ __launch_bounds__(256,4) void gat_kernel(
    const float* __restrict__ agent_qs,
    const float* __restrict__ obs_ls,
    const float* __restrict__ adj_ls,
    const _Float16* __restrict__ whf,    // [17][4][64][8]
    const _Float16* __restrict__ wo1f,   // [32][4][64][8]
    const _Float16* __restrict__ wodf,   // [2][4][64][8]
    const float* __restrict__ wa_g,      // [4][128]
    const float* __restrict__ b_all_ws,
    const float* __restrict__ dis_ws,
    const float* __restrict__ vv_ws,
    float* __restrict__ out){
  __shared__ __align__(16) _Float16 arena_h[16384];   // 4 wave slots of 4096 h -> zh -> part/hyp
  __shared__ __align__(16) float adj_s[1024];
  __shared__ float qs_s[64];
  __shared__ float y_s[64];

  const int t = threadIdx.x, w = t>>6, lane = t&63, lg = lane>>4, li = lane&15;
  const int bb = blockIdx.x*4;
  const int b = bb + w;
  const v4f ZERO4 = {0.f,0.f,0.f,0.f};

  // thread t loads exactly its own wave's batch adj (t>>6 == w)
  reinterpret_cast<float4*>(adj_s)[t] =
      reinterpret_cast<const float4*>(adj_ls + (size_t)bb*256)[t];
  if (t < 64) qs_s[t] = agent_qs[bb*NAG + t];

  _Float16* slot   = arena_h + (w<<12);
  _Float16* att_h  = slot;                                  // [8][16][16], g-stride 272
  float*    uv_f   = reinterpret_cast<float*>(slot + 2176); // [8][32]: u@g*32, v@g*32+16
  float*    u2v2_f = reinterpret_cast<float*>(slot + 2688); // [4][16]: u1,v1,uf,vf
  float*    att2_f = reinterpret_cast<float*>(slot + 2816); // [2][16*17]

  // ---- P1: Wh = obs @ Wcat + fused u/v tile ----
  const float* ob = obs_ls + (size_t)b*(NAG*OBSD) + li*OBSD + lg*8;
  v8h aob[4];
  #pragma unroll
  for (int kk=0;kk<4;++kk){
    v4f f0 = *reinterpret_cast<const v4f*>(ob + kk*32);
    v4f f1 = *reinterpret_cast<const v4f*>(ob + kk*32 + 4);
    v8h h;
    #pragma unroll
    for (int jj=0;jj<4;++jj){ h[jj]=(_Float16)f0[jj]; h[4+jj]=(_Float16)f1[jj]; }
    aob[kk]=h;
  }
  v4h whB[16];
  #pragma unroll
  for (int nt=0;nt<16;++nt){
    v4f d = ZERO4;
    #pragma unroll
    for (int kk=0;kk<4;++kk){
      v8h bf = *reinterpret_cast<const v8h*>(whf + (size_t)(((nt*4+kk)<<6) + lane)*8);
      d = MFMA32(aob[kk], bf, d);
    }
    v4h hh;
    #pragma unroll
    for (int r=0;r<4;++r) hh[r]=(_Float16)d[r];
    whB[nt]=hh;
  }
  {
    v4f d = ZERO4;
    #pragma unroll
    for (int kk=0;kk<4;++kk){
      v8h bf = *reinterpret_cast<const v8h*>(whf + (size_t)(((64+kk)<<6) + lane)*8);
      d = MFMA32(aob[kk], bf, d);
    }
    #pragma unroll
    for (int r=0;r<4;++r)
      uv_f[(li>>1)*32 + (li&1)*16 + lg*4 + r] = d[r];
  }

  // ---- P2: att = softmax_i(mask(lrelu(u_i+v_j))); 2 cols/lane; f16 pair stores ----
  {
    const float* adj_w = adj_s + w*256;
    int cc = lane*2;
    int g = cc>>4, j0 = cc&15;       // j0 even, both cols same g
    float vj0 = uv_f[g*32+16+j0], vj1 = uv_f[g*32+16+j0+1];
    float e0[16], e1[16];
    float m0=-INFINITY, m1=-INFINITY;
    #pragma unroll
    for (int i=0;i<16;++i){
      float u = uv_f[g*32+i];
      float x0 = lrelu(u+vj0), x1 = lrelu(u+vj1);
      x0 = (adj_w[i*16+j0]   > 0.f) ? x0 : NEGV;
      x1 = (adj_w[i*16+j0+1] > 0.f) ? x1 : NEGV;
      e0[i]=x0; e1[i]=x1;
      m0=fmaxf(m0,x0); m1=fmaxf(m1,x1);
    }
    float s0=0.f,s1=0.f;
    #pragma unroll
    for (int i=0;i<16;++i){ e0[i]=__expf(e0[i]-m0); e1[i]=__expf(e1[i]-m1); s0+=e0[i]; s1+=e1[i]; }
    float inv0=1.f/s0, inv1=1.f/s1;
    #pragma unroll
    for (int i=0;i<16;++i){
      union { unsigned u32; _Float16 h[2]; } pk;
      pk.h[0]=(_Float16)(e0[i]*inv0);
      pk.h[1]=(_Float16)(e1[i]*inv1);
      *reinterpret_cast<unsigned*>(&att_h[g*272 + i*16 + j0]) = pk.u32;
    }
  }

  // ---- P3: xcat = elu(att @ Wh); u2/v2 partials on the fly ----
  v4h xcB[16];
  float p2[4][4];
  #pragma unroll
  for (int k4=0;k4<4;++k4)
    #pragma unroll
    for (int r=0;r<4;++r) p2[k4][r]=0.f;
  #pragma unroll
  for (int g=0;g<8;++g){
    v4h afr = *reinterpret_cast<const v4h*>(&att_h[g*272 + li*16 + lg*4]);
    int side = g>>2;
    #pragma unroll
    for (int h2=0;h2<2;++h2){
      int nt = g*2+h2;
      v4f d = ZERO4;
      d = MFMA16(afr, whB[nt], d);
      int cl = (nt - side*8)*16 + li;
      float wu = wa_g[side*256 + cl];
      float wv = wa_g[side*256 + 128 + cl];
      v4h hh;
      #pragma unroll
      for (int r=0;r<4;++r){
        float e = eluf(d[r]);
        hh[r]=(_Float16)e;
        p2[side*2][r]   += e*wu;
        p2[side*2+1][r] += e*wv;
      }
      xcB[nt]=hh;
    }
  }
  #pragma unroll
  for (int off=1; off<16; off<<=1)
    #pragma unroll
    for (int k4=0;k4<4;++k4)
      #pragma unroll
      for (int r=0;r<4;++r) p2[k4][r] += __shfl_xor(p2[k4][r], off, 64);
  if (li==0){
    #pragma unroll
    for (int k4=0;k4<4;++k4)
      #pragma unroll
      for (int r=0;r<4;++r) u2v2_f[k4*16 + lg*4 + r] = p2[k4][r];
  }

  // ---- ATT2: both second-layer attentions for own batch ----
  if (lane < 32){
    int side = lane>>4, j = lane&15;
    const float* adj_w = adj_s + w*256;
    float vj = u2v2_f[side*32 + 16 + j];
    float ev[16]; float m=-INFINITY;
    #pragma unroll
    for (int i=0;i<16;++i){
      float x = lrelu(u2v2_f[side*32 + i] + vj);
      x = (adj_w[i*16+j] > 0.f) ? x : NEGV;
      ev[i]=x; m=fmaxf(m,x);
    }
    float ss=0.f;
    #pragma unroll
    for (int i=0;i<16;++i){ ev[i]=__expf(ev[i]-m); ss+=ev[i]; }
    float inv=1.f/ss;
    #pragma unroll
    for (int i=0;i<16;++i) att2_f[side*272 + j*17 + i] = ev[i]*inv;
  }

  // ---- Z: z^T = xcat^T @ att2^T; pack to A-frag order in own slot ----
  v4h bat0, bat1;
  #pragma unroll
  for (int jj=0;jj<4;++jj){
    bat0[jj] = (_Float16)att2_f[(lg*4+jj)*17 + li];
    bat1[jj] = (_Float16)att2_f[272 + (lg*4+jj)*17 + li];
  }
  #pragma unroll
  for (int side=0;side<2;++side){
    v4h bat = side ? bat1 : bat0;
    #pragma unroll
    for (int ct=0;ct<8;++ct){
      v4f zD = ZERO4;
      zD = MFMA16(xcB[side*8+ct], bat, zD);
      int kk = ct>>1;
      int lp = li + 16*((ct&1)*2 + (lg>>1));
      _Float16* dst = slot + side*2048 + kk*512 + lp*8 + (lg&1)*4;
      union { unsigned u32; _Float16 h[2]; } q0,q1;
      q0.h[0]=(_Float16)zD[0]; q0.h[1]=(_Float16)zD[1];
      q1.h[0]=(_Float16)zD[2]; q1.h[1]=(_Float16)zD[3];
      *reinterpret_cast<unsigned*>(dst)   = q0.u32;
      *reinterpret_cast<unsigned*>(dst+2) = q1.u32;
    }
  }
  __syncthreads();   // B1: all zh ready

  // ---- load A-frags: az1 all 4 batches, azf own ----
  v8h az1[4][4];
  #pragma unroll
  for (int b4=0;b4<4;++b4)
    #pragma unroll
    for (int kk=0;kk<4;++kk)
      az1[b4][kk] = *reinterpret_cast<const v8h*>(arena_h + (b4<<12) + kk*512 + lane*8);
  v8h azf[4];
  #pragma unroll
  for (int kk=0;kk<4;++kk)
    azf[kk] = *reinterpret_cast<const v8h*>(arena_h + (w<<12) + 2048 + kk*512 + lane*8);

  // gf out-GEMM (own batch)
  v4f ofD[2];
  #pragma unroll
  for (int nt2=0;nt2<2;++nt2){
    v4f d = ZERO4;
    #pragma unroll
    for (int kk=0;kk<4;++kk){
      v8h bf = *reinterpret_cast<const v8h*>(wodf + (size_t)(((nt2*4+kk)<<6)+lane)*8);
      d = MFMA32(azf[kk], bf, d);
    }
    ofD[nt2]=d;
  }
  __syncthreads();   // B2: all az loads done; arena reusable

  float* part = reinterpret_cast<float*>(arena_h);   // [w4][b4][16][16]
  float* hyp  = part + 4096;                         // [b4][512]

  // gf epilogue -> hyp
  #pragma unroll
  for (int nt2=0;nt2<2;++nt2){
    float x[4];
    #pragma unroll
    for (int r=0;r<4;++r) x[r]=eluf(ofD[nt2][r]);
    float m = fmaxf(fmaxf(x[0],x[1]),fmaxf(x[2],x[3]));
    m = fmaxf(m, __shfl_xor(m,16,64));
    m = fmaxf(m, __shfl_xor(m,32,64));
    float s = __expf(x[0]-m)+__expf(x[1]-m)+__expf(x[2]-m)+__expf(x[3]-m);
    s += __shfl_xor(s,16,64);
    s += __shfl_xor(s,32,64);
    float ls = m + __logf(s);
    #pragma unroll
    for (int r=0;r<4;++r)
      hyp[w*512 + (lg*4+r)*32 + nt2*16 + li] = fabsf(x[r]-ls);
  }

  // g1 joint out-GEMM: wave's 8 nt (one e-half, 8 n-agents) x 4 batches
  {
    const int base = (w>>1) + ((w&1)<<4);
    float pa[4][4];
    #pragma unroll
    for (int b4=0;b4<4;++b4)
      #pragma unroll
      for (int r=0;r<4;++r) pa[b4][r]=0.f;
    #pragma unroll
    for (int n8=0;n8<8;++n8){
      int nt = base + 2*n8;
      v8h bf[4];
      #pragma unroll
      for (int kk=0;kk<4;++kk)
        bf[kk] = *reinterpret_cast<const v8h*>(wo1f + (size_t)(((nt*4+kk)<<6)+lane)*8);
      #pragma unroll
      for (int b4=0;b4<4;++b4){
        v4f d = ZERO4;
        #pragma unroll
        for (int kk=0;kk<4;++kk) d = MFMA32(az1[b4][kk], bf[kk], d);
        float x[4];
        #pragma unroll
        for (int r=0;r<4;++r) x[r]=eluf(d[r]);
        float m = fmaxf(fmaxf(x[0],x[1]),fmaxf(x[2],x[3]));
        m = fmaxf(m, __shfl_xor(m,16,64));
        m = fmaxf(m, __shfl_xor(m,32,64));
        float s = __expf(x[0]-m)+__expf(x[1]-m)+__expf(x[2]-m)+__expf(x[3]-m);
        s += __shfl_xor(s,16,64);
        s += __shfl_xor(s,32,64);
        float ls = m + __logf(s);
        float q = qs_s[b4*16 + (nt>>1)];
        #pragma unroll
        for (int r=0;r<4;++r) pa[b4][r] += q*fabsf(x[r]-ls);
      }
    }
    #pragma unroll
    for (int b4=0;b4<4;++b4)
      #pragma unroll
      for (int r=0;r<4;++r)
        part[(w*4+b4)*256 + (lg*4+r)*16 + li] = pa[b4][r];
  }
  __syncthreads();   // B3: part + hyp ready

  // ---- hidden = elu(b_all + part) * hyp; reduce ----
  {
    int b2 = t>>6, i2 = (t>>2)&15, q8 = t&3;
    const float* ba = b_all_ws + (size_t)(bb+b2)*512 + i2*32;
    float ps = 0.f;
    #pragma unroll
    for (int e8=0;e8<8;++e8){
      int e = q8*8 + e8;
      int eh = e>>4;
      float s = ba[e]
              + part[((eh*2  )*4 + b2)*256 + i2*16 + (e&15)]
              + part[((eh*2+1)*4 + b2)*256 + i2*16 + (e&15)];
      ps += eluf(s) * hyp[b2*512 + i2*32 + e];
    }
    ps += __shfl_xor(ps,1,64);
    ps += __shfl_xor(ps,2,64);
    if (q8==0) y_s[b2*16+i2] = ps * dis_ws[(size_t)(bb+b2)*NAG + i2];
  }
  __syncthreads();   // B4
  if (t < 4){
    float q = vv_ws[bb+t];
    #pragma unroll
    for (int i=0;i<16;++i) q += y_s[t*16+i];
    out[bb+t] = q;
  }
}

extern "C" void kernel_launch(void* const* d_in, const int* in_sizes, int n_in,
                              void* d_out, int out_size, void* d_ws, size_t ws_size,
                              hipStream_t stream) {
  const float* agent_qs = (const float*)d_in[0];
  const float* states   = (const float*)d_in[1];
  const float* obs_ls   = (const float*)d_in[2];
  const float* adj_ls   = (const float*)d_in[3];
  const float* wn_w     = (const float*)d_in[4];
  const float* wn_b     = (const float*)d_in[5];
  const float* g1_Wh    = (const float*)d_in[6];
  const float* g1_ah    = (const float*)d_in[7];
  const float* g1_Wout  = (const float*)d_in[8];
  const float* g1_aout  = (const float*)d_in[9];
  const float* gf_Wh    = (const float*)d_in[10];
  const float* gf_ah    = (const float*)d_in[11];
  const float* gf_Wout  = (const float*)d_in[12];
  const float* gf_aout  = (const float*)d_in[13];
  const float* hb_W     = (const float*)d_in[14];
  const float* hb_b     = (const float*)d_in[15];
  const float* v1_w     = (const float*)d_in[16];
  const float* v1_b     = (const float*)d_in[17];
  const float* v2_w     = (const float*)d_in[18];
  const float* v2_b     = (const float*)d_in[19];

  float* ws    = (float*)d_ws;
  float* b_all = ws;                          // 8192*512
  float* dis   = b_all + (size_t)BTOT*512;    // 8192*16
  float* vvv   = dis + (size_t)BTOT*NAG;      // 8192
  float* wa    = vvv + BTOT;                  // 512
  _Float16* whf  = (_Float16*)(wa + 512);     // 34816 h
  _Float16* wo1f = whf + 34816;               // 65536 h
  _Float16* wodf = wo1f + 65536;              // 4096 h
  _Float16* wstf = wodf + 4096;               // 143360 h

  prep2_kernel<<<dim3(1), dim3(128), 0, stream>>>(g1_Wout, g1_aout, gf_Wout, gf_aout, wa);
  pack_wh_kernel<<<dim3(136), dim3(256), 0, stream>>>(g1_Wh, gf_Wh, g1_ah, gf_ah, whf);
  pack_wout_kernel<<<dim3(272), dim3(256), 0, stream>>>(g1_Wout, gf_Wout, wo1f, wodf);
  pack_wst_kernel<<<dim3(560), dim3(256), 0, stream>>>(hb_W, wn_w, v1_w, wstf);
  st_kernel<<<dim3(BTOT/16), dim3(256), 0, stream>>>(states, wstf, hb_b, wn_b, v1_b, v2_w, v2_b,
                                                     b_all, dis, vvv);
  gat_kernel<<<dim3(BTOT/4), dim3(256), 0, stream>>>(agent_qs, obs_ls, adj_ls,
                                                     whf, wo1f, wodf, wa,
                                                     b_all, dis, vvv, (float*)d_out);
}